// Round 4
// baseline (691.477 us; speedup 1.0000x reference)
//
#include <hip/hip_runtime.h>

// Problem constants (from reference): N=256, V=4, L=100000.
// out[n][v][l] = mask[n][l] ? (cats[n][l] == v ? 1 : 0) : s[n][v][l]
//
// Memory-bound elementwise select, ideal traffic 1.024 GB (irreducible:
// mask is per-element random so s line-granularity reads can't be skipped).
// R4: MLP experiment — LPT=16 (4x float4 per plane in flight), plain loads,
// NT stores only. If neutral vs 192us, declare mixed-stream HBM roofline.

#define N_SEQ 256
#define V_VOCAB 4
#define L_LEN 100000
#define LPT 16                   // l-positions per thread
#define L_CHUNKS (L_LEN / LPT)   // 6250, exact

typedef int   vint4   __attribute__((ext_vector_type(4)));
typedef float vfloat4 __attribute__((ext_vector_type(4)));

__global__ __launch_bounds__(256)
void mutate_kernel(const float* __restrict__ s,
                   const int* __restrict__ mask,
                   const int* __restrict__ cats,
                   float* __restrict__ out) {
    const int lc = blockIdx.x * blockDim.x + threadIdx.x;   // chunk index in L
    if (lc >= L_CHUNKS) return;
    const int n = blockIdx.y;

    const int l0 = lc * LPT;
    const long long nl = (long long)n * L_LEN + l0;

    vint4 m[4], c[4];
    #pragma unroll
    for (int q = 0; q < 4; ++q) {
        m[q] = *(reinterpret_cast<const vint4*>(mask + nl) + q);
        c[q] = *(reinterpret_cast<const vint4*>(cats + nl) + q);
    }

    #pragma unroll
    for (int v = 0; v < V_VOCAB; ++v) {
        const long long off = ((long long)n * V_VOCAB + v) * L_LEN + l0;
        vfloat4 sv[4];
        #pragma unroll
        for (int q = 0; q < 4; ++q)
            sv[q] = *(reinterpret_cast<const vfloat4*>(s + off) + q);
        #pragma unroll
        for (int q = 0; q < 4; ++q) {
            vfloat4 o;
            #pragma unroll
            for (int j = 0; j < 4; ++j)
                o[j] = m[q][j] ? (c[q][j] == v ? 1.0f : 0.0f) : sv[q][j];
            __builtin_nontemporal_store(o, reinterpret_cast<vfloat4*>(out + off) + q);
        }
    }
}

extern "C" void kernel_launch(void* const* d_in, const int* in_sizes, int n_in,
                              void* d_out, int out_size, void* d_ws, size_t ws_size,
                              hipStream_t stream) {
    const float* s    = (const float*)d_in[0];   // (N, V, L) float32 one-hot
    const int*   mask = (const int*)d_in[1];     // (N, L) bool -> int32
    const int*   cats = (const int*)d_in[2];     // (N, L) int32
    float* out = (float*)d_out;                  // (N, V, L) float32

    const int block = 256;
    dim3 grid((L_CHUNKS + block - 1) / block, N_SEQ);   // (25, 256)
    mutate_kernel<<<grid, block, 0, stream>>>(s, mask, cats, out);
}

// Round 5
// 192.608 us; speedup vs baseline: 3.5901x; 3.5901x over previous
//
#include <hip/hip_runtime.h>

// Problem constants (from reference): N=256, V=4, L=100000.
// out[n][v][l] = mask[n][l] ? (cats[n][l] == v ? 1 : 0) : s[n][v][l]
//
// Memory-bound elementwise select, ideal traffic 1.024 GB.
// R5: full per-instruction coalescing (thread owns ONE float4 per access,
// adjacent lanes adjacent addresses — R4's 64B/thread chunks caused 2.4x
// write amplification). U=2 chunks per thread spaced by blockDim for MLP.
// Plain loads/stores (NT proved neutral in R3).

#define N_SEQ 256
#define V_VOCAB 4
#define L_LEN 100000
#define CHUNKS (L_LEN / 4)       // 25000 float4 chunks per (n,v) row
#define BLOCK 256
#define U 2                      // chunks per thread, blockDim-strided
#define TILE (BLOCK * U)         // 512 chunks per block
#define FULL_BLOCKS (CHUNKS / TILE)   // 48 full blocks; 49th handles tail

typedef int   vint4   __attribute__((ext_vector_type(4)));
typedef float vfloat4 __attribute__((ext_vector_type(4)));

__device__ __forceinline__ void do_chunk(const float* __restrict__ s,
                                         const int* __restrict__ mask,
                                         const int* __restrict__ cats,
                                         float* __restrict__ out,
                                         int n, int chunk) {
    const long long nl = (long long)n * L_LEN + (long long)chunk * 4;
    const vint4 m = *reinterpret_cast<const vint4*>(mask + nl);
    const vint4 c = *reinterpret_cast<const vint4*>(cats + nl);
    #pragma unroll
    for (int v = 0; v < V_VOCAB; ++v) {
        const long long off = ((long long)n * V_VOCAB + v) * L_LEN
                            + (long long)chunk * 4;
        const vfloat4 sv = *reinterpret_cast<const vfloat4*>(s + off);
        vfloat4 o;
        #pragma unroll
        for (int j = 0; j < 4; ++j)
            o[j] = m[j] ? (c[j] == v ? 1.0f : 0.0f) : sv[j];
        *reinterpret_cast<vfloat4*>(out + off) = o;
    }
}

__global__ __launch_bounds__(BLOCK)
void mutate_kernel(const float* __restrict__ s,
                   const int* __restrict__ mask,
                   const int* __restrict__ cats,
                   float* __restrict__ out) {
    const int n = blockIdx.y;
    const int c0 = blockIdx.x * TILE + threadIdx.x;   // chunk 0
    if (blockIdx.x < FULL_BLOCKS) {
        // hot path: both chunks in range, no branches
        do_chunk(s, mask, cats, out, n, c0);
        do_chunk(s, mask, cats, out, n, c0 + BLOCK);
    } else {
        if (c0 < CHUNKS)         do_chunk(s, mask, cats, out, n, c0);
        if (c0 + BLOCK < CHUNKS) do_chunk(s, mask, cats, out, n, c0 + BLOCK);
    }
}

extern "C" void kernel_launch(void* const* d_in, const int* in_sizes, int n_in,
                              void* d_out, int out_size, void* d_ws, size_t ws_size,
                              hipStream_t stream) {
    const float* s    = (const float*)d_in[0];   // (N, V, L) float32 one-hot
    const int*   mask = (const int*)d_in[1];     // (N, L) bool -> int32
    const int*   cats = (const int*)d_in[2];     // (N, L) int32
    float* out = (float*)d_out;                  // (N, V, L) float32

    dim3 grid((CHUNKS + TILE - 1) / TILE, N_SEQ);   // (49, 256)
    mutate_kernel<<<grid, BLOCK, 0, stream>>>(s, mask, cats, out);
}